// Round 5
// baseline (231.179 us; speedup 1.0000x reference)
//
#include <hip/hip_runtime.h>

#define NKEYS 64
#define BATCH 8   // int4 loads in flight per thread = 128 B

typedef float vfloat4 __attribute__((ext_vector_type(4)));

__device__ __forceinline__ float bperm_f(int lane_idx, int src_i) {
    return __int_as_float(__builtin_amdgcn_ds_bpermute(lane_idx << 2, src_i));
}

// out[i] = t[x[i]], t[v] = b[k] iff keys[k] == (float)v, else 0.
// Per-lane table value built in registers (6-step bpermute binary search over
// sorted keys, once per wave), then parked in LDS. Per-element lookup is a
// ds_read_b32 gather: 64 fp32 entries over 32 banks = at most 2 entries/bank
// -> worst-case 2-way aliasing, which is free (m136).
// 8 int4 bulk loads issue before any use; the single __syncthreads only needs
// lgkmcnt(0) (bulk loads target private VGPRs), so reads stay in flight across
// the barrier and drain pipelined against the gather+store tail.
__global__ __launch_bounds__(256) void sel_xform_kernel(
    const int4* __restrict__ in,
    const float* __restrict__ b,
    const float* __restrict__ keys,
    float* __restrict__ out,
    int nvec, int ntail, const int* __restrict__ in_tail, float* __restrict__ out_tail)
{
    __shared__ float t[NKEYS];
    const int tid  = threadIdx.x;
    const int lane = tid & 63;

    // Table-source loads first (vmcnt completes in order: waiting on these
    // does not wait on the bulk loads issued after them).
    const float kv = keys[lane];   // lane l holds keys[l]
    const float bv = b[lane];      // lane l holds b[l]

    // Bulk input loads: 8 x 16B per thread, all issued before any use.
    const int base = blockIdx.x * (256 * BATCH) + tid;
    int4 v[BATCH];
    bool p[BATCH];
    #pragma unroll
    for (int j = 0; j < BATCH; ++j) {
        const int idx = base + j * 256;
        p[j] = idx < nvec;
        if (p[j]) v[j] = in[idx];
        else      v[j] = int4{0, 0, 0, 0};
    }

    // Per-lane table entry: lower_bound of (float)lane in keys[0..63].
    const int   kv_i   = __float_as_int(kv);
    const float target = (float)lane;
    int pos = 0;
    #pragma unroll
    for (int s = 32; s >= 1; s >>= 1) {
        const float kc = bperm_f(pos + s - 1, kv_i);   // keys[pos+s-1]
        if (kc < target) pos += s;
    }
    const int posc = (pos > NKEYS - 1) ? (NKEYS - 1) : pos;  // jnp.clip
    const float kmatch = bperm_f(posc, kv_i);
    const float bval   = bperm_f(posc, __float_as_int(bv));
    const float tv     = (kmatch == target) ? bval : 0.0f;   // t[lane]

    if (tid < NKEYS) t[tid] = tv;   // wave 0 parks the table
    __syncthreads();

    // Gather + store, draining the bulk loads in order.
    #pragma unroll
    for (int j = 0; j < BATCH; ++j) {
        if (p[j]) {
            const int4 x = v[j];
            vfloat4 o;
            o.x = ((unsigned)x.x < NKEYS) ? t[x.x] : 0.0f;
            o.y = ((unsigned)x.y < NKEYS) ? t[x.y] : 0.0f;
            o.z = ((unsigned)x.z < NKEYS) ? t[x.z] : 0.0f;
            o.w = ((unsigned)x.w < NKEYS) ? t[x.w] : 0.0f;
            *(vfloat4*)(out + ((long)(base + j * 256) << 2)) = o;
        }
    }

    // Scalar tail (n % 4 elements): uniform scalar scan, no cross-lane ops.
    if (blockIdx.x == 0 && tid < ntail) {
        const float xf = (float)in_tail[tid];
        float r = 0.0f;
        for (int k = 0; k < NKEYS; ++k) r = (keys[k] == xf) ? b[k] : r;  // keys unique
        out_tail[tid] = r;
    }
}

extern "C" void kernel_launch(void* const* d_in, const int* in_sizes, int n_in,
                              void* d_out, int out_size, void* d_ws, size_t ws_size,
                              hipStream_t stream) {
    const int*   x    = (const int*)d_in[0];     // inputs, int32, [8,4096,1024]
    const float* b    = (const float*)d_in[1];   // per-key bias, [64]
    const float* keys = (const float*)d_in[2];   // sorted unique keys, [64]
    float* out = (float*)d_out;

    const int n     = in_sizes[0];
    const int nvec  = n >> 2;        // int4 / float4 groups
    const int ntail = n & 3;

    // 2048 int4 per 256-thread block (8 per thread).
    int grid = (nvec + 2047) / 2048;
    if (grid < 1) grid = 1;          // block 0 must exist for the tail

    sel_xform_kernel<<<grid, 256, 0, stream>>>(
        (const int4*)x, b, keys, out,
        nvec, ntail, x + (nvec << 2), out + (nvec << 2));
}